// Round 4
// baseline (707.472 us; speedup 1.0000x reference)
//
#include <hip/hip_runtime.h>
#include <math.h>

#define NN 50000
#define NE 800000
#define HD 128
#define FD 16
#define NPATH 16
#define PL 8
#define NM 6
#define NS 320
#define NB 196   // ceil(NN/256)
#define AK 320   // padded K for fused GEMM (hsum128 | h128 | ef16 | deg | 1 | pad)
#define AKU 160  // uints per A row
#define NEGV -1000000000.0f

typedef unsigned int uint;
typedef unsigned short ushort;
typedef short bf16x8 __attribute__((ext_vector_type(8)));
typedef float f32x4 __attribute__((ext_vector_type(4)));

__device__ __forceinline__ float sigm(float x){ return 1.0f/(1.0f+expf(-x)); }

__device__ __forceinline__ ushort f2b(float f){
    union{float f; uint u;} v; v.f=f;
    uint r = v.u + 0x7FFFu + ((v.u>>16)&1u);
    return (ushort)(r>>16);
}
__device__ __forceinline__ float b2f(ushort s){
    union{uint u; float f;} v; v.u = ((uint)s)<<16; return v.f;
}
__device__ __forceinline__ float blo(uint v){ return b2f((ushort)(v&0xFFFF)); }
__device__ __forceinline__ float bhi(uint v){ return b2f((ushort)(v>>16)); }
__device__ __forceinline__ uint pack2(float a, float b){ return (uint)f2b(a) | (((uint)f2b(b))<<16); }

// ---- degree histogram ----
__global__ void k_deg(const int* __restrict__ ei, int* __restrict__ deg){
    int e = blockIdx.x*256 + threadIdx.x;
    if (e >= NE) return;
    atomicAdd(&deg[ei[NE + e]], 1);
}

// ---- hierarchical exclusive scan ----
__global__ void k_scan1(const int* __restrict__ deg, int* __restrict__ offs, int* __restrict__ bsum){
    int tid = threadIdx.x, bid = blockIdx.x;
    int idx = bid*256 + tid;
    int v = (idx<NN) ? deg[idx] : 0;
    int lane = tid&63, w = tid>>6;
    int x = v;
    #pragma unroll
    for (int d=1; d<64; d<<=1){ int y = __shfl_up(x,d); if (lane>=d) x += y; }
    __shared__ int wsum[4];
    if (lane==63) wsum[w] = x;
    __syncthreads();
    int base = 0;
    #pragma unroll
    for (int j=0;j<4;j++) if (j<w) base += wsum[j];
    if (idx<NN) offs[idx] = base + x - v;
    if (tid==255) bsum[bid] = base + x;
}
__global__ void k_scan2(int* __restrict__ bsum, int* __restrict__ offs){
    int tid = threadIdx.x;
    int v = (tid<NB) ? bsum[tid] : 0;
    int lane = tid&63, w = tid>>6;
    int x = v;
    #pragma unroll
    for (int d=1; d<64; d<<=1){ int y = __shfl_up(x,d); if (lane>=d) x += y; }
    __shared__ int wsum[4];
    if (lane==63) wsum[w] = x;
    __syncthreads();
    int base = 0;
    #pragma unroll
    for (int j=0;j<4;j++) if (j<w) base += wsum[j];
    if (tid<NB) bsum[tid] = base + x - v;
    if (tid==255) offs[NN] = base + x;
}
__global__ void k_scan3(const int* __restrict__ bsum, int* __restrict__ offs, int* __restrict__ cursor){
    int idx = blockIdx.x*256 + threadIdx.x;
    if (idx>=NN) return;
    int o = offs[idx] + bsum[blockIdx.x];
    offs[idx]=o; cursor[idx]=o;
}

// ---- fill CSR with src node + edge id ----
__global__ void k_fill(const int* __restrict__ ei, int* __restrict__ cursor,
                       int* __restrict__ csr_src, int* __restrict__ csr_eid){
    int e = blockIdx.x*256 + threadIdx.x;
    if (e >= NE) return;
    int dst = ei[NE+e];
    int src = ei[e];
    int pos = atomicAdd(&cursor[dst], 1);
    csr_src[pos] = src;
    csr_eid[pos] = e;
}

// ---- per-node 16-wide sums of edge_feat (by eid) and node_feat (by src) ----
__global__ void k_gat16(const int* __restrict__ csr_eid, const int* __restrict__ csr_src,
                        const float* __restrict__ edge_feat, const float* __restrict__ nf,
                        const int* __restrict__ offs,
                        float* __restrict__ ef_sum, float* __restrict__ nf_sum){
    int node = blockIdx.x*4 + (threadIdx.x>>6);
    int lane = threadIdx.x & 63;
    int k = lane & 15, sub = lane >> 4;
    int b = offs[node], e2 = offs[node+1];
    float ae = 0.f, an = 0.f;
    int i = b + sub;
    for (; i + 4 < e2; i += 8){
        int e0 = csr_eid[i], e1 = csr_eid[i+4];
        int s0 = csr_src[i], s1 = csr_src[i+4];
        float f0 = edge_feat[(size_t)e0*FD + k];
        float g0 = nf[(size_t)s0*FD + k];
        float f1 = edge_feat[(size_t)e1*FD + k];
        float g1 = nf[(size_t)s1*FD + k];
        ae += f0 + f1; an += g0 + g1;
    }
    if (i < e2){
        int e0 = csr_eid[i]; int s0 = csr_src[i];
        ae += edge_feat[(size_t)e0*FD + k];
        an += nf[(size_t)s0*FD + k];
    }
    ae += __shfl_xor(ae, 16); ae += __shfl_xor(ae, 32);
    an += __shfl_xor(an, 16); an += __shfl_xor(an, 32);
    if (sub == 0){ ef_sum[node*FD + k] = ae; nf_sum[node*FD + k] = an; }
}

// ---- Wf = W_ep@W_e ; bfv = b_ep@W_e + b_msg ----
__global__ void k_folds(const float* __restrict__ W_ep, const float* __restrict__ b_ep,
                        const float* __restrict__ W_msg, const float* __restrict__ b_msg,
                        float* __restrict__ Wf, float* __restrict__ bfv){
    int o = blockIdx.x*256 + threadIdx.x;
    if (o < FD*HD){
        int k=o>>7, c=o&127;
        float acc=0.f;
        for (int m=0;m<HD;m++) acc += W_ep[k*HD+m]*W_msg[(HD+m)*HD+c];
        Wf[o]=acc;
    } else if (o < FD*HD+HD){
        int c=o-FD*HD;
        float acc=b_msg[c];
        for (int m=0;m<HD;m++) acc += b_ep[m]*W_msg[(HD+m)*HD+c];
        bfv[c]=acc;
    }
}

// ---- build folded mega-weight W2T[512][320], col = 4*j + gate ----
// gates: 0=Xr, 1=Xz, 2=Xin(gi_n), 3=Xhn(gh_n)
__global__ void k_wprep2(const float* __restrict__ W_ih, const float* __restrict__ W_hh,
                         const float* __restrict__ W_msg, const float* __restrict__ Wf,
                         const float* __restrict__ bfv,
                         const float* __restrict__ b_ih, const float* __restrict__ b_hh,
                         ushort* __restrict__ W2T){
    int c = blockIdx.x;       // 0..511
    int k = threadIdx.x;      // 0..319
    int j = c>>2, g = c&3;
    float v = 0.f;
    if (k < 128){
        if (g < 3){
            const float* wm = W_msg + (size_t)k*HD;          // W_h row k
            const float* wi = W_ih + (size_t)(g*HD+j)*HD;
            float acc=0.f;
            for (int m=0;m<HD;m++) acc += wm[m]*wi[m];
            v = acc;
        }
    } else if (k < 256){
        int kk = k-128;
        if (g==0)      v = W_hh[(size_t)j*HD+kk];
        else if (g==1) v = W_hh[(size_t)(HD+j)*HD+kk];
        else if (g==3) v = W_hh[(size_t)(2*HD+j)*HD+kk];
    } else if (k < 272){
        if (g < 3){
            const float* wf = Wf + (size_t)(k-256)*HD;
            const float* wi = W_ih + (size_t)(g*HD+j)*HD;
            float acc=0.f;
            for (int m=0;m<HD;m++) acc += wf[m]*wi[m];
            v = acc;
        }
    } else if (k == 272){
        if (g < 3){
            const float* wi = W_ih + (size_t)(g*HD+j)*HD;
            float acc=0.f;
            for (int m=0;m<HD;m++) acc += bfv[m]*wi[m];
            v = acc;
        }
    } else if (k == 273){
        v = (g==0)? b_ih[j]+b_hh[j] : (g==1)? b_ih[HD+j]+b_hh[HD+j]
          : (g==2)? b_ih[2*HD+j] : b_hh[2*HD+j];
    }
    W2T[(size_t)c*AK + k] = f2b(v);
}

// ---- prep A0: h0, hsum1 = nf_sum@W_np + deg*b_np ; statics into A0 & A1 ----
__global__ void k_prep(const float* __restrict__ nf, const float* __restrict__ nf_sum,
                       const int* __restrict__ deg, const float* __restrict__ W_np,
                       const float* __restrict__ b_np, const float* __restrict__ ef_sum,
                       ushort* __restrict__ A0, ushort* __restrict__ A1){
    int idx = blockIdx.x*256 + threadIdx.x;  // NN*64
    int n = idx>>6, c2 = idx&63;
    int j = c2*2;
    const float* x = nf + (size_t)n*FD;
    const float* s = nf_sum + (size_t)n*FD;
    float d = (float)deg[n];
    float h0a = b_np[j], h0b = b_np[j+1];
    float hsa = d*b_np[j], hsb = d*b_np[j+1];
    #pragma unroll
    for (int k=0;k<FD;k++){
        float w0 = W_np[k*HD+j], w1 = W_np[k*HD+j+1];
        float xv = x[k], sv = s[k];
        h0a += xv*w0; h0b += xv*w1;
        hsa += sv*w0; hsb += sv*w1;
    }
    uint* a0 = (uint*)A0;
    a0[(size_t)n*AKU + 64 + c2] = pack2(h0a,h0b);
    a0[(size_t)n*AKU + c2]      = pack2(hsa,hsb);
    if (c2 < 32){
        int col = 256 + c2*2;
        float v0 = (col<272)? ef_sum[n*FD + (col-256)] : (col==272)? d : 0.f;
        float v1 = (col+1<272)? ef_sum[n*FD + (col+1-256)] : (col+1==273)? 1.f : 0.f;
        uint pv = pack2(v0,v1);
        a0[(size_t)n*AKU + 128 + c2] = pv;
        ((uint*)A1)[(size_t)n*AKU + 128 + c2] = pv;
    }
}

// ---- fused GEMM (K=320, col-interleaved gates) + GRU epilogue -> Anxt h-slot ----
__global__ __launch_bounds__(256) void k_fused(const ushort* __restrict__ A,
                                               const ushort* __restrict__ Bt,
                                               ushort* __restrict__ Anxt){
    __shared__ __align__(16) short As[128*64];
    __shared__ __align__(16) short Bs[128*64];
    const int tid = threadIdx.x;
    const int lane = tid & 63, w = tid>>6;
    const int wm = w>>1, wn = w&1;
    const int m0 = blockIdx.x*128;
    const int n0 = blockIdx.y*128;
    f32x4 acc[4][4] = {};
    for (int kk=0; kk<5; ++kk){
        __syncthreads();
        #pragma unroll
        for (int i=0;i<4;i++){
            int id = tid + i*256;
            int row = id>>3, s = id&7;
            int phys = row*64 + ((s ^ (row&7))<<3);
            int ar = m0 + row; if (ar >= NN) ar = NN-1;
            *(int4*)&As[phys] = *(const int4*)(A + (size_t)ar*AK + kk*64 + s*8);
            *(int4*)&Bs[phys] = *(const int4*)(Bt + (size_t)(n0+row)*AK + kk*64 + s*8);
        }
        __syncthreads();
        #pragma unroll
        for (int ksel=0; ksel<2; ++ksel){
            bf16x8 af[4], bfr[4];
            #pragma unroll
            for (int t=0;t<4;t++){
                int arow = wm*64 + t*16 + (lane&15);
                int aslot = (ksel*4 + (lane>>4)) ^ (arow&7);
                af[t] = *(const bf16x8*)&As[arow*64 + aslot*8];
                int brow = wn*64 + t*16 + (lane&15);
                int bslot = (ksel*4 + (lane>>4)) ^ (brow&7);
                bfr[t] = *(const bf16x8*)&Bs[brow*64 + bslot*8];
            }
            #pragma unroll
            for (int mi=0;mi<4;mi++)
                #pragma unroll
                for (int ni=0;ni<4;ni++)
                    acc[mi][ni] = __builtin_amdgcn_mfma_f32_16x16x32_bf16(af[mi], bfr[ni], acc[mi][ni], 0,0,0);
        }
    }
    // GRU epilogue: col = n0 + wn*64 + ni*16 + (lane&15) = 4*j + g
    const int lane4 = lane & ~3;
    #pragma unroll
    for (int mi=0;mi<4;mi++){
        #pragma unroll
        for (int ni=0;ni<4;ni++){
            int cloc = wn*64 + ni*16 + (lane&15);
            int j = (n0 + cloc)>>2;
            #pragma unroll
            for (int r=0;r<4;r++){
                float v = acc[mi][ni][r];
                float xr  = __shfl(v, lane4+0);
                float xz  = __shfl(v, lane4+1);
                float xin = __shfl(v, lane4+2);
                float xhn = __shfl(v, lane4+3);
                int row = m0 + wm*64 + mi*16 + (lane>>4)*4 + r;
                ushort u = 0;
                if ((lane&3)==0 && row<NN){
                    float rr = sigm(xr), zz = sigm(xz);
                    float nn2 = tanhf(xin + rr*xhn);
                    float ho = b2f(A[(size_t)row*AK + 128 + j]);
                    u = f2b((1.f-zz)*nn2 + zz*ho);
                }
                int up = __shfl((int)(uint)u, (lane+4)&63);
                if ((lane&7)==0 && row<NN)
                    ((uint*)Anxt)[(size_t)row*AKU + 64 + (j>>1)] = (uint)u | (((uint)up)<<16);
            }
        }
    }
}

// ---- hsum[n] = sum over in-edges of h[src] (within same A buffer) ----
__global__ void k_gather(ushort* __restrict__ A, const int* __restrict__ offs,
                         const int* __restrict__ csr_src){
    int node = blockIdx.x*4 + (threadIdx.x>>6);
    int c2 = threadIdx.x & 63;
    int b = offs[node], e2 = offs[node+1];
    float a0 = 0.f, a1 = 0.f;
    const uint* hp = (const uint*)A;
    int i = b;
    for (; i + 8 <= e2; i += 8){
        int s0=csr_src[i],  s1=csr_src[i+1], s2=csr_src[i+2], s3=csr_src[i+3];
        int s4=csr_src[i+4],s5=csr_src[i+5], s6=csr_src[i+6], s7=csr_src[i+7];
        uint v0=hp[(size_t)s0*AKU+64+c2], v1=hp[(size_t)s1*AKU+64+c2],
             v2=hp[(size_t)s2*AKU+64+c2], v3=hp[(size_t)s3*AKU+64+c2],
             v4=hp[(size_t)s4*AKU+64+c2], v5=hp[(size_t)s5*AKU+64+c2],
             v6=hp[(size_t)s6*AKU+64+c2], v7=hp[(size_t)s7*AKU+64+c2];
        a0 += blo(v0)+blo(v1)+blo(v2)+blo(v3)+blo(v4)+blo(v5)+blo(v6)+blo(v7);
        a1 += bhi(v0)+bhi(v1)+bhi(v2)+bhi(v3)+bhi(v4)+bhi(v5)+bhi(v6)+bhi(v7);
    }
    if (i + 4 <= e2){
        int s0=csr_src[i],s1=csr_src[i+1],s2=csr_src[i+2],s3=csr_src[i+3];
        uint v0=hp[(size_t)s0*AKU+64+c2], v1=hp[(size_t)s1*AKU+64+c2],
             v2=hp[(size_t)s2*AKU+64+c2], v3=hp[(size_t)s3*AKU+64+c2];
        a0 += blo(v0)+blo(v1)+blo(v2)+blo(v3);
        a1 += bhi(v0)+bhi(v1)+bhi(v2)+bhi(v3);
        i += 4;
    }
    for (; i < e2; ++i){
        uint v = hp[(size_t)csr_src[i]*AKU+64+c2];
        a0 += blo(v); a1 += bhi(v);
    }
    ((uint*)A)[(size_t)node*AKU + c2] = pack2(a0,a1);
}

// ---- column sums of final h ----
__global__ void k_sum(const ushort* __restrict__ A, float* __restrict__ gsum){
    int c2 = threadIdx.x & 63;
    int rs = blockIdx.x*4 + (threadIdx.x>>6);
    float a0=0.f, a1=0.f;
    const uint* hp = (const uint*)A;
    for (int n=rs; n<NN; n+=1024){
        uint v = hp[(size_t)n*AKU + 64 + c2];
        a0 += blo(v); a1 += bhi(v);
    }
    atomicAdd(&gsum[2*c2],   a0);
    atomicAdd(&gsum[2*c2+1], a1);
}

// ---- tiny agents + value head, wave-parallel reductions ----
__global__ void k_small(const float* __restrict__ ef, const int* __restrict__ paths,
                        const int* __restrict__ pmask, const float* __restrict__ pfeat,
                        const int* __restrict__ mmask, const int* __restrict__ smask,
                        const float* __restrict__ pspec,
                        const float* __restrict__ W_ep, const float* __restrict__ b_ep,
                        const float* __restrict__ W_path, const float* __restrict__ b_path,
                        const float* __restrict__ W_mod, const float* __restrict__ b_mod,
                        const float* __restrict__ c1w, const float* __restrict__ c1b,
                        const float* __restrict__ c2w, const float* __restrict__ c2b,
                        const float* __restrict__ W_val, const float* __restrict__ b_val,
                        const float* __restrict__ gsum, float* __restrict__ out){
    __shared__ float z[NPATH][HD];
    __shared__ float lf[NS];
    __shared__ float spec[NS];
    __shared__ float red[8];
    __shared__ float scal[3];
    __shared__ int   sel[3];
    __shared__ float maxsh;
    int tid = threadIdx.x, lane = tid&63, w = tid>>6;

    { // z[p][c] for 16 paths
        int pr = tid>>7, c = tid&127;
        #pragma unroll
        for (int pb=0; pb<4; pb++){
            int p = pb*4 + pr;
            float acc = 0.f;
            for (int l=0;l<PL;l++){
                int eid = paths[p*PL + l];
                const float* f = ef + (size_t)eid*FD;
                #pragma unroll
                for (int k=0;k<FD;k++) acc += f[k]*W_ep[k*HD + c];
            }
            z[p][c] = acc*0.125f + b_ep[c];
        }
    }
    __syncthreads();
    { // logits_p: 16 paths x 32 threads
        int p = tid>>5, sub = tid&31;
        float part = 0.f;
        #pragma unroll
        for (int c=sub;c<HD;c+=32) part += z[p][c]*W_path[c];
        #pragma unroll
        for (int d=16; d>=1; d>>=1) part += __shfl_xor(part, d);
        if (sub==0) lf[p] = (pmask[p]==0)? NEGV : part + b_path[0];
    }
    __syncthreads();
    if (w==0){ // softmax+argmax over 16
        float v = (lane<NPATH)? lf[lane] : -3.0e38f;
        float m = v;
        #pragma unroll
        for (int d=1; d<64; d<<=1) m = fmaxf(m, __shfl_xor(m, d));
        float e = (lane<NPATH)? expf(v-m) : 0.f;
        #pragma unroll
        for (int d=1; d<64; d<<=1) e += __shfl_xor(e, d);
        int idx = (lane<NPATH && v==m)? lane : (1<<30);
        #pragma unroll
        for (int d=1; d<64; d<<=1) idx = min(idx, __shfl_xor(idx, d));
        if (lane==0){ sel[0]=idx; scal[0] = -logf(e); }
    }
    __syncthreads();
    int pstar = sel[0];
    if (w < NM){ // logits_m: one wave per m
        float part = 0.f;
        #pragma unroll
        for (int c=lane;c<HD;c+=64) part += z[pstar][c]*W_mod[c*NM + w];
        if (lane<3) part += pfeat[pstar*3+lane]*W_mod[(HD+lane)*NM + w];
        #pragma unroll
        for (int d=1; d<64; d<<=1) part += __shfl_xor(part, d);
        if (lane==0) red[w] = (mmask[pstar*NM + w]==0)? NEGV : part + b_mod[w];
    } else if (w == 7){ // value head
        float part = gsum[lane]*W_val[lane] + gsum[lane+64]*W_val[lane+64];
        #pragma unroll
        for (int d=1; d<64; d<<=1) part += __shfl_xor(part, d);
        if (lane==0) scal[2] = part/(float)NN + b_val[0];
    }
    __syncthreads();
    if (w==0){ // softmax+argmax over 6
        float v = (lane<NM)? red[lane] : -3.0e38f;
        float m = v;
        #pragma unroll
        for (int d=1; d<64; d<<=1) m = fmaxf(m, __shfl_xor(m, d));
        float e = (lane<NM)? expf(v-m) : 0.f;
        #pragma unroll
        for (int d=1; d<64; d<<=1) e += __shfl_xor(e, d);
        int idx = (lane<NM && v==m)? lane : (1<<30);
        #pragma unroll
        for (int d=1; d<64; d<<=1) idx = min(idx, __shfl_xor(idx, d));
        if (lane==0){ sel[1]=idx; scal[1] = -logf(e); }
    }
    __syncthreads();
    int mstar = sel[1];
    if (tid < NS) spec[tid] = pspec[pstar*NS + tid];
    __syncthreads();
    float v = -3.0e38f;
    if (tid < NS){
        float acc = c2b[0];
        #pragma unroll
        for (int ch=0; ch<8; ch++){
            float a = c1b[ch];
            #pragma unroll
            for (int k=0;k<5;k++){
                int ss = tid + k - 2;
                if (ss>=0 && ss<NS) a += spec[ss]*c1w[ch*5+k];
            }
            a = fmaxf(a, 0.f);
            acc += a*c2w[ch];
        }
        v = (smask[pstar*NM*NS + mstar*NS + tid]==0) ? NEGV : acc;
    }
    float m = v;
    #pragma unroll
    for (int d=1; d<64; d<<=1) m = fmaxf(m, __shfl_xor(m, d));
    if (lane==0) red[w] = m;
    __syncthreads();
    if (tid==0){
        float mm = red[0];
        #pragma unroll
        for (int i=1;i<8;i++) mm = fmaxf(mm, red[i]);
        maxsh = mm; sel[2] = 1<<30;
    }
    __syncthreads();
    float M2 = maxsh;
    if (tid<NS && v==M2) atomicMin(&sel[2], tid);
    float e = (tid<NS)? expf(v-M2) : 0.f;
    #pragma unroll
    for (int d=1; d<64; d<<=1) e += __shfl_xor(e, d);
    if (lane==0) red[w] = e;
    __syncthreads();
    if (tid==0){
        float se = 0.f;
        #pragma unroll
        for (int i=0;i<8;i++) se += red[i];
        out[0] = (float)pstar;
        out[1] = (float)sel[2];
        out[2] = (float)mstar;
        out[3] = scal[0] + scal[1] - logf(se);
        out[4] = scal[2];
    }
}

extern "C" void kernel_launch(void* const* d_in, const int* in_sizes, int n_in,
                              void* d_out, int out_size, void* d_ws, size_t ws_size,
                              hipStream_t stream) {
    (void)in_sizes; (void)n_in; (void)out_size; (void)ws_size;
    const float* node_feat     = (const float*)d_in[0];
    const float* edge_feat     = (const float*)d_in[1];
    const int*   edge_index    = (const int*)d_in[2];
    const int*   paths         = (const int*)d_in[3];
    const int*   path_mask     = (const int*)d_in[4];
    const float* path_features = (const float*)d_in[5];
    const int*   mod_masks     = (const int*)d_in[6];
    const int*   spec_masks    = (const int*)d_in[7];
    const float* path_spectrum = (const float*)d_in[8];
    const float* W_np  = (const float*)d_in[9];
    const float* b_np  = (const float*)d_in[10];
    const float* W_ep  = (const float*)d_in[11];
    const float* b_ep  = (const float*)d_in[12];
    const float* W_msg = (const float*)d_in[13];
    const float* b_msg = (const float*)d_in[14];
    const float* W_ih  = (const float*)d_in[15];
    const float* b_ih  = (const float*)d_in[16];
    const float* W_hh  = (const float*)d_in[17];
    const float* b_hh  = (const float*)d_in[18];
    const float* W_path = (const float*)d_in[19];
    const float* b_path = (const float*)d_in[20];
    const float* W_mod  = (const float*)d_in[21];
    const float* b_mod  = (const float*)d_in[22];
    const float* c1w = (const float*)d_in[23];
    const float* c1b = (const float*)d_in[24];
    const float* c2w = (const float*)d_in[25];
    const float* c2b = (const float*)d_in[26];
    const float* W_val = (const float*)d_in[27];
    const float* b_val = (const float*)d_in[28];

    char* ws = (char*)d_ws;
    size_t off = 0;
    auto alloc = [&](size_t bytes)->char*{
        char* p = ws + off;
        off += (bytes + 255) & ~(size_t)255;
        return p;
    };
    int*    deg     = (int*)alloc((size_t)NN*4);
    int*    offs    = (int*)alloc((size_t)(NN+1)*4);
    int*    cursor  = (int*)alloc((size_t)NN*4);
    int*    bsum    = (int*)alloc((size_t)NB*4);
    int*    csr_src = (int*)alloc((size_t)NE*4);
    int*    csr_eid = (int*)alloc((size_t)NE*4);
    float*  ef_sum  = (float*)alloc((size_t)NN*FD*4);
    float*  nf_sum  = (float*)alloc((size_t)NN*FD*4);
    float*  Wf      = (float*)alloc((size_t)FD*HD*4);
    float*  bfv     = (float*)alloc((size_t)HD*4);
    ushort* W2T     = (ushort*)alloc((size_t)512*AK*2);
    ushort* A0      = (ushort*)alloc((size_t)NN*AK*2);
    ushort* A1      = (ushort*)alloc((size_t)NN*AK*2);
    float*  gsum    = (float*)alloc((size_t)HD*4);

    hipMemsetAsync(deg, 0, (size_t)NN*4, stream);
    hipMemsetAsync(gsum, 0, (size_t)HD*4, stream);

    k_deg<<<(NE+255)/256, 256, 0, stream>>>(edge_index, deg);
    k_scan1<<<NB, 256, 0, stream>>>(deg, offs, bsum);
    k_scan2<<<1, 256, 0, stream>>>(bsum, offs);
    k_scan3<<<NB, 256, 0, stream>>>(bsum, offs, cursor);
    k_fill<<<(NE+255)/256, 256, 0, stream>>>(edge_index, cursor, csr_src, csr_eid);
    k_gat16<<<NN/4, 256, 0, stream>>>(csr_eid, csr_src, edge_feat, node_feat, offs, ef_sum, nf_sum);
    k_folds<<<9, 256, 0, stream>>>(W_ep, b_ep, W_msg, b_msg, Wf, bfv);
    k_wprep2<<<512, AK, 0, stream>>>(W_ih, W_hh, W_msg, Wf, bfv, b_ih, b_hh, W2T);
    k_prep<<<NN*64/256, 256, 0, stream>>>(node_feat, nf_sum, deg, W_np, b_np, ef_sum, A0, A1);

    const int MB = (NN+127)/128;   // 391
    // iter 1: A0 -> A1
    k_fused<<<dim3(MB,4), 256, 0, stream>>>(A0, W2T, A1);
    // iter 2: gather(A1), A1 -> A0
    k_gather<<<NN/4, 256, 0, stream>>>(A1, offs, csr_src);
    k_fused<<<dim3(MB,4), 256, 0, stream>>>(A1, W2T, A0);
    // iter 3: gather(A0), A0 -> A1
    k_gather<<<NN/4, 256, 0, stream>>>(A0, offs, csr_src);
    k_fused<<<dim3(MB,4), 256, 0, stream>>>(A0, W2T, A1);

    k_sum<<<256, 256, 0, stream>>>(A1, gsum);
    k_small<<<1, 512, 0, stream>>>(edge_feat, paths, path_mask, path_features,
                                   mod_masks, spec_masks, path_spectrum,
                                   W_ep, b_ep, W_path, b_path, W_mod, b_mod,
                                   c1w, c1b, c2w, c2b, W_val, b_val,
                                   gsum, (float*)d_out);
}

// Round 5
// 463.116 us; speedup vs baseline: 1.5276x; 1.5276x over previous
//
#include <hip/hip_runtime.h>
#include <math.h>

#define NN 50000
#define NE 800000
#define HD 128
#define FD 16
#define NPATH 16
#define PL 8
#define NM 6
#define NS 320
#define NB 196   // ceil(NN/256)
#define AK 320   // K for fused GEMM (hsum128 | h128 | ef16 | deg | 1 | pad)
#define AKU 160  // uints per A row
#define NEGV -1000000000.0f

typedef unsigned int uint;
typedef unsigned short ushort;
typedef short bf16x8 __attribute__((ext_vector_type(8)));
typedef float f32x4 __attribute__((ext_vector_type(4)));

__device__ __forceinline__ float sigm(float x){ return 1.0f/(1.0f+expf(-x)); }

__device__ __forceinline__ ushort f2b(float f){
    union{float f; uint u;} v; v.f=f;
    uint r = v.u + 0x7FFFu + ((v.u>>16)&1u);
    return (ushort)(r>>16);
}
__device__ __forceinline__ float b2f(ushort s){
    union{uint u; float f;} v; v.u = ((uint)s)<<16; return v.f;
}
__device__ __forceinline__ float blo(uint v){ return b2f((ushort)(v&0xFFFF)); }
__device__ __forceinline__ float bhi(uint v){ return b2f((ushort)(v>>16)); }
__device__ __forceinline__ uint pack2(float a, float b){ return (uint)f2b(a) | (((uint)f2b(b))<<16); }

// ---- degree histogram ----
__global__ void k_deg(const int* __restrict__ ei, int* __restrict__ deg){
    int e = blockIdx.x*256 + threadIdx.x;
    if (e >= NE) return;
    atomicAdd(&deg[ei[NE + e]], 1);
}

// ---- hierarchical exclusive scan ----
__global__ void k_scan1(const int* __restrict__ deg, int* __restrict__ offs, int* __restrict__ bsum){
    int tid = threadIdx.x, bid = blockIdx.x;
    int idx = bid*256 + tid;
    int v = (idx<NN) ? deg[idx] : 0;
    int lane = tid&63, w = tid>>6;
    int x = v;
    #pragma unroll
    for (int d=1; d<64; d<<=1){ int y = __shfl_up(x,d); if (lane>=d) x += y; }
    __shared__ int wsum[4];
    if (lane==63) wsum[w] = x;
    __syncthreads();
    int base = 0;
    #pragma unroll
    for (int j=0;j<4;j++) if (j<w) base += wsum[j];
    if (idx<NN) offs[idx] = base + x - v;
    if (tid==255) bsum[bid] = base + x;
}
__global__ void k_scan2(int* __restrict__ bsum, int* __restrict__ offs){
    int tid = threadIdx.x;
    int v = (tid<NB) ? bsum[tid] : 0;
    int lane = tid&63, w = tid>>6;
    int x = v;
    #pragma unroll
    for (int d=1; d<64; d<<=1){ int y = __shfl_up(x,d); if (lane>=d) x += y; }
    __shared__ int wsum[4];
    if (lane==63) wsum[w] = x;
    __syncthreads();
    int base = 0;
    #pragma unroll
    for (int j=0;j<4;j++) if (j<w) base += wsum[j];
    if (tid<NB) bsum[tid] = base + x - v;
    if (tid==255) offs[NN] = base + x;
}
__global__ void k_scan3(const int* __restrict__ bsum, int* __restrict__ offs, int* __restrict__ cursor){
    int idx = blockIdx.x*256 + threadIdx.x;
    if (idx>=NN) return;
    int o = offs[idx] + bsum[blockIdx.x];
    offs[idx]=o; cursor[idx]=o;
}

// ---- fill CSR with src node + edge id ----
__global__ void k_fill(const int* __restrict__ ei, int* __restrict__ cursor,
                       int* __restrict__ csr_src, int* __restrict__ csr_eid){
    int e = blockIdx.x*256 + threadIdx.x;
    if (e >= NE) return;
    int dst = ei[NE+e];
    int src = ei[e];
    int pos = atomicAdd(&cursor[dst], 1);
    csr_src[pos] = src;
    csr_eid[pos] = e;
}

// ---- per-node 16-wide sums of edge_feat (by eid) and node_feat (by src) ----
__global__ void k_gat16(const int* __restrict__ csr_eid, const int* __restrict__ csr_src,
                        const float* __restrict__ edge_feat, const float* __restrict__ nf,
                        const int* __restrict__ offs,
                        float* __restrict__ ef_sum, float* __restrict__ nf_sum){
    int node = blockIdx.x*4 + (threadIdx.x>>6);
    int lane = threadIdx.x & 63;
    int k = lane & 15, sub = lane >> 4;
    int b = offs[node], e2 = offs[node+1];
    float ae = 0.f, an = 0.f;
    int i = b + sub;
    for (; i + 4 < e2; i += 8){
        int e0 = csr_eid[i], e1 = csr_eid[i+4];
        int s0 = csr_src[i], s1 = csr_src[i+4];
        float f0 = edge_feat[(size_t)e0*FD + k];
        float g0 = nf[(size_t)s0*FD + k];
        float f1 = edge_feat[(size_t)e1*FD + k];
        float g1 = nf[(size_t)s1*FD + k];
        ae += f0 + f1; an += g0 + g1;
    }
    if (i < e2){
        int e0 = csr_eid[i]; int s0 = csr_src[i];
        ae += edge_feat[(size_t)e0*FD + k];
        an += nf[(size_t)s0*FD + k];
    }
    ae += __shfl_xor(ae, 16); ae += __shfl_xor(ae, 32);
    an += __shfl_xor(an, 16); an += __shfl_xor(an, 32);
    if (sub == 0){ ef_sum[node*FD + k] = ae; nf_sum[node*FD + k] = an; }
}

// ---- Wf = W_ep@W_e ; bfv = b_ep@W_e + b_msg ----
__global__ void k_folds(const float* __restrict__ W_ep, const float* __restrict__ b_ep,
                        const float* __restrict__ W_msg, const float* __restrict__ b_msg,
                        float* __restrict__ Wf, float* __restrict__ bfv){
    int o = blockIdx.x*256 + threadIdx.x;
    if (o < FD*HD){
        int k=o>>7, c=o&127;
        float acc=0.f;
        for (int m=0;m<HD;m++) acc += W_ep[k*HD+m]*W_msg[(HD+m)*HD+c];
        Wf[o]=acc;
    } else if (o < FD*HD+HD){
        int c=o-FD*HD;
        float acc=b_msg[c];
        for (int m=0;m<HD;m++) acc += b_ep[m]*W_msg[(HD+m)*HD+c];
        bfv[c]=acc;
    }
}

// ---- build folded mega-weight W2T[512][320], gate-blocked: col = g*128 + j ----
// gates: 0=r, 1=z, 2=gi_n, 3=gh_n. Biases folded into k=273 (constant-1 column).
__global__ void k_wprep2(const float* __restrict__ W_ih, const float* __restrict__ W_hh,
                         const float* __restrict__ W_msg, const float* __restrict__ Wf,
                         const float* __restrict__ bfv,
                         const float* __restrict__ b_ih, const float* __restrict__ b_hh,
                         ushort* __restrict__ W2T){
    int c = blockIdx.x;       // 0..511
    int k = threadIdx.x;      // 0..319
    int g = c>>7, j = c&127;
    float v = 0.f;
    if (k < 128){
        if (g < 3){   // hsum path: (W_h @ W_ih_g^T)
            const float* wm = W_msg + (size_t)k*HD;
            const float* wi = W_ih + (size_t)(g*HD+j)*HD;
            float acc=0.f;
            for (int m=0;m<HD;m++) acc += wm[m]*wi[m];
            v = acc;
        }
    } else if (k < 256){      // h path: W_hh gates (none for gi_n)
        int kk = k-128;
        if (g==0)      v = W_hh[(size_t)j*HD+kk];
        else if (g==1) v = W_hh[(size_t)(HD+j)*HD+kk];
        else if (g==3) v = W_hh[(size_t)(2*HD+j)*HD+kk];
    } else if (k < 272){      // ef_sum path
        if (g < 3){
            const float* wf = Wf + (size_t)(k-256)*HD;
            const float* wi = W_ih + (size_t)(g*HD+j)*HD;
            float acc=0.f;
            for (int m=0;m<HD;m++) acc += wf[m]*wi[m];
            v = acc;
        }
    } else if (k == 272){     // deg path
        if (g < 3){
            const float* wi = W_ih + (size_t)(g*HD+j)*HD;
            float acc=0.f;
            for (int m=0;m<HD;m++) acc += bfv[m]*wi[m];
            v = acc;
        }
    } else if (k == 273){     // constant-1: biases
        v = (g==0)? b_ih[j]+b_hh[j] : (g==1)? b_ih[HD+j]+b_hh[HD+j]
          : (g==2)? b_ih[2*HD+j] : b_hh[2*HD+j];
    }
    W2T[(size_t)c*AK + k] = f2b(v);
}

// ---- prep A0: h0 = nf@W_np+b_np ; hsum1 = nf_sum@W_np + deg*b_np ; statics -> A0 & A1 ----
__global__ void k_prep(const float* __restrict__ nf, const float* __restrict__ nf_sum,
                       const int* __restrict__ deg, const float* __restrict__ W_np,
                       const float* __restrict__ b_np, const float* __restrict__ ef_sum,
                       ushort* __restrict__ A0, ushort* __restrict__ A1){
    int idx = blockIdx.x*256 + threadIdx.x;  // NN*64
    int n = idx>>6, c2 = idx&63;
    int j = c2*2;
    const float* x = nf + (size_t)n*FD;
    const float* s = nf_sum + (size_t)n*FD;
    float d = (float)deg[n];
    float h0a = b_np[j], h0b = b_np[j+1];
    float hsa = d*b_np[j], hsb = d*b_np[j+1];
    #pragma unroll
    for (int k=0;k<FD;k++){
        float w0 = W_np[k*HD+j], w1 = W_np[k*HD+j+1];
        float xv = x[k], sv = s[k];
        h0a += xv*w0; h0b += xv*w1;
        hsa += sv*w0; hsb += sv*w1;
    }
    uint* a0 = (uint*)A0;
    a0[(size_t)n*AKU + 64 + c2] = pack2(h0a,h0b);
    a0[(size_t)n*AKU + c2]      = pack2(hsa,hsb);
    if (c2 < 32){
        int col = 256 + c2*2;
        float v0 = (col<272)? ef_sum[n*FD + (col-256)] : (col==272)? d : 0.f;
        float v1 = (col+1<272)? ef_sum[n*FD + (col+1-256)] : (col+1==273)? 1.f : 0.f;
        uint pv = pack2(v0,v1);
        a0[(size_t)n*AKU + 128 + c2] = pv;
        ((uint*)A1)[(size_t)n*AKU + 128 + c2] = pv;
    }
}

// ---- G[NN][512] = A[NN][320] @ W2T[512][320]^T, 128x128 tile, K=320 ----
__global__ __launch_bounds__(256) void k_gemmG(const ushort* __restrict__ A,
                                               const ushort* __restrict__ Bt,
                                               ushort* __restrict__ G){
    __shared__ __align__(16) short As[128*64];
    __shared__ __align__(16) short Bs[128*64];
    const int tid = threadIdx.x;
    const int lane = tid & 63, w = tid>>6;
    const int wm = w>>1, wn = w&1;
    const int m0 = blockIdx.x*128, n0 = blockIdx.y*128;
    f32x4 acc[4][4] = {};
    for (int kk=0; kk<5; ++kk){
        __syncthreads();
        #pragma unroll
        for (int i=0;i<4;i++){
            int id = tid + i*256;
            int row = id>>3, s = id&7;
            int phys = row*64 + ((s ^ (row&7))<<3);
            int ar = m0 + row; if (ar >= NN) ar = NN-1;
            *(int4*)&As[phys] = *(const int4*)(A + (size_t)ar*AK + kk*64 + s*8);
            *(int4*)&Bs[phys] = *(const int4*)(Bt + (size_t)(n0+row)*AK + kk*64 + s*8);
        }
        __syncthreads();
        #pragma unroll
        for (int ksel=0; ksel<2; ++ksel){
            bf16x8 af[4], bfr[4];
            #pragma unroll
            for (int t=0;t<4;t++){
                int arow = wm*64 + t*16 + (lane&15);
                int aslot = (ksel*4 + (lane>>4)) ^ (arow&7);
                af[t] = *(const bf16x8*)&As[arow*64 + aslot*8];
                int brow = wn*64 + t*16 + (lane&15);
                int bslot = (ksel*4 + (lane>>4)) ^ (brow&7);
                bfr[t] = *(const bf16x8*)&Bs[brow*64 + bslot*8];
            }
            #pragma unroll
            for (int mi=0;mi<4;mi++)
                #pragma unroll
                for (int ni=0;ni<4;ni++)
                    acc[mi][ni] = __builtin_amdgcn_mfma_f32_16x16x32_bf16(af[mi], bfr[ni], acc[mi][ni], 0,0,0);
        }
    }
    #pragma unroll
    for (int mi=0;mi<4;mi++){
        #pragma unroll
        for (int r=0;r<4;r++){
            int row = m0 + wm*64 + mi*16 + (lane>>4)*4 + r;
            if (row >= NN) continue;
            #pragma unroll
            for (int ni=0;ni<4;ni++){
                int col = n0 + wn*64 + ni*16 + (lane&15);
                G[(size_t)row*512 + col] = f2b(acc[mi][ni][r]);
            }
        }
    }
}

// ---- GRU epilogue: G=[r|z|in|hn] (biases pre-folded) + A.h -> Anxt.h ----
__global__ void k_gruep(const ushort* __restrict__ G, const ushort* __restrict__ A,
                        ushort* __restrict__ Anxt){
    int idx = blockIdx.x*256 + threadIdx.x;   // NN*64
    int n = idx>>6, c2 = idx&63;
    const uint* g = (const uint*)G + (size_t)n*256;
    uint vr = g[c2], vz = g[64+c2], vin = g[128+c2], vhn = g[192+c2];
    uint vh = ((const uint*)A)[(size_t)n*AKU + 64 + c2];
    float r0 = sigm(blo(vr)), r1 = sigm(bhi(vr));
    float z0 = sigm(blo(vz)), z1 = sigm(bhi(vz));
    float n0 = tanhf(blo(vin) + r0*blo(vhn));
    float n1 = tanhf(bhi(vin) + r1*bhi(vhn));
    float h0 = (1.f-z0)*n0 + z0*blo(vh);
    float h1 = (1.f-z1)*n1 + z1*bhi(vh);
    ((uint*)Anxt)[(size_t)n*AKU + 64 + c2] = pack2(h0,h1);
}

// ---- hsum[n] = sum over in-edges of h[src] (within same A buffer) ----
__global__ void k_gather(ushort* __restrict__ A, const int* __restrict__ offs,
                         const int* __restrict__ csr_src){
    int node = blockIdx.x*4 + (threadIdx.x>>6);
    int c2 = threadIdx.x & 63;
    int b = offs[node], e2 = offs[node+1];
    float a0 = 0.f, a1 = 0.f;
    const uint* hp = (const uint*)A;
    int i = b;
    for (; i + 8 <= e2; i += 8){
        int s0=csr_src[i],  s1=csr_src[i+1], s2=csr_src[i+2], s3=csr_src[i+3];
        int s4=csr_src[i+4],s5=csr_src[i+5], s6=csr_src[i+6], s7=csr_src[i+7];
        uint v0=hp[(size_t)s0*AKU+64+c2], v1=hp[(size_t)s1*AKU+64+c2],
             v2=hp[(size_t)s2*AKU+64+c2], v3=hp[(size_t)s3*AKU+64+c2],
             v4=hp[(size_t)s4*AKU+64+c2], v5=hp[(size_t)s5*AKU+64+c2],
             v6=hp[(size_t)s6*AKU+64+c2], v7=hp[(size_t)s7*AKU+64+c2];
        a0 += blo(v0)+blo(v1)+blo(v2)+blo(v3)+blo(v4)+blo(v5)+blo(v6)+blo(v7);
        a1 += bhi(v0)+bhi(v1)+bhi(v2)+bhi(v3)+bhi(v4)+bhi(v5)+bhi(v6)+bhi(v7);
    }
    if (i + 4 <= e2){
        int s0=csr_src[i],s1=csr_src[i+1],s2=csr_src[i+2],s3=csr_src[i+3];
        uint v0=hp[(size_t)s0*AKU+64+c2], v1=hp[(size_t)s1*AKU+64+c2],
             v2=hp[(size_t)s2*AKU+64+c2], v3=hp[(size_t)s3*AKU+64+c2];
        a0 += blo(v0)+blo(v1)+blo(v2)+blo(v3);
        a1 += bhi(v0)+bhi(v1)+bhi(v2)+bhi(v3);
        i += 4;
    }
    for (; i < e2; ++i){
        uint v = hp[(size_t)csr_src[i]*AKU+64+c2];
        a0 += blo(v); a1 += bhi(v);
    }
    ((uint*)A)[(size_t)node*AKU + c2] = pack2(a0,a1);
}

// ---- column sums of final h ----
__global__ void k_sum(const ushort* __restrict__ A, float* __restrict__ gsum){
    int c2 = threadIdx.x & 63;
    int rs = blockIdx.x*4 + (threadIdx.x>>6);
    float a0=0.f, a1=0.f;
    const uint* hp = (const uint*)A;
    for (int n=rs; n<NN; n+=1024){
        uint v = hp[(size_t)n*AKU + 64 + c2];
        a0 += blo(v); a1 += bhi(v);
    }
    atomicAdd(&gsum[2*c2],   a0);
    atomicAdd(&gsum[2*c2+1], a1);
}

// ---- tiny agents + value head, wave-parallel ----
__global__ void k_small(const float* __restrict__ ef, const int* __restrict__ paths,
                        const int* __restrict__ pmask, const float* __restrict__ pfeat,
                        const int* __restrict__ mmask, const int* __restrict__ smask,
                        const float* __restrict__ pspec,
                        const float* __restrict__ W_ep, const float* __restrict__ b_ep,
                        const float* __restrict__ W_path, const float* __restrict__ b_path,
                        const float* __restrict__ W_mod, const float* __restrict__ b_mod,
                        const float* __restrict__ c1w, const float* __restrict__ c1b,
                        const float* __restrict__ c2w, const float* __restrict__ c2b,
                        const float* __restrict__ W_val, const float* __restrict__ b_val,
                        const float* __restrict__ gsum, float* __restrict__ out){
    __shared__ float z[NPATH][HD];
    __shared__ float lf[NS];
    __shared__ float spec[NS];
    __shared__ float red[8];
    __shared__ float scal[3];
    __shared__ int   sel[3];
    __shared__ float maxsh;
    int tid = threadIdx.x, lane = tid&63, w = tid>>6;

    { // z[p][c] for 16 paths
        int pr = tid>>7, c = tid&127;
        #pragma unroll
        for (int pb=0; pb<4; pb++){
            int p = pb*4 + pr;
            float acc = 0.f;
            for (int l=0;l<PL;l++){
                int eid = paths[p*PL + l];
                const float* f = ef + (size_t)eid*FD;
                #pragma unroll
                for (int k=0;k<FD;k++) acc += f[k]*W_ep[k*HD + c];
            }
            z[p][c] = acc*0.125f + b_ep[c];
        }
    }
    __syncthreads();
    { // logits_p
        int p = tid>>5, sub = tid&31;
        float part = 0.f;
        #pragma unroll
        for (int c=sub;c<HD;c+=32) part += z[p][c]*W_path[c];
        #pragma unroll
        for (int d=16; d>=1; d>>=1) part += __shfl_xor(part, d);
        if (sub==0) lf[p] = (pmask[p]==0)? NEGV : part + b_path[0];
    }
    __syncthreads();
    if (w==0){
        float v = (lane<NPATH)? lf[lane] : -3.0e38f;
        float m = v;
        #pragma unroll
        for (int d=1; d<64; d<<=1) m = fmaxf(m, __shfl_xor(m, d));
        float e = (lane<NPATH)? expf(v-m) : 0.f;
        #pragma unroll
        for (int d=1; d<64; d<<=1) e += __shfl_xor(e, d);
        int idx = (lane<NPATH && v==m)? lane : (1<<30);
        #pragma unroll
        for (int d=1; d<64; d<<=1) idx = min(idx, __shfl_xor(idx, d));
        if (lane==0){ sel[0]=idx; scal[0] = -logf(e); }
    }
    __syncthreads();
    int pstar = sel[0];
    if (w < NM){
        float part = 0.f;
        #pragma unroll
        for (int c=lane;c<HD;c+=64) part += z[pstar][c]*W_mod[c*NM + w];
        if (lane<3) part += pfeat[pstar*3+lane]*W_mod[(HD+lane)*NM + w];
        #pragma unroll
        for (int d=1; d<64; d<<=1) part += __shfl_xor(part, d);
        if (lane==0) red[w] = (mmask[pstar*NM + w]==0)? NEGV : part + b_mod[w];
    } else if (w == 7){
        float part = gsum[lane]*W_val[lane] + gsum[lane+64]*W_val[lane+64];
        #pragma unroll
        for (int d=1; d<64; d<<=1) part += __shfl_xor(part, d);
        if (lane==0) scal[2] = part/(float)NN + b_val[0];
    }
    __syncthreads();
    if (w==0){
        float v = (lane<NM)? red[lane] : -3.0e38f;
        float m = v;
        #pragma unroll
        for (int d=1; d<64; d<<=1) m = fmaxf(m, __shfl_xor(m, d));
        float e = (lane<NM)? expf(v-m) : 0.f;
        #pragma unroll
        for (int d=1; d<64; d<<=1) e += __shfl_xor(e, d);
        int idx = (lane<NM && v==m)? lane : (1<<30);
        #pragma unroll
        for (int d=1; d<64; d<<=1) idx = min(idx, __shfl_xor(idx, d));
        if (lane==0){ sel[1]=idx; scal[1] = -logf(e); }
    }
    __syncthreads();
    int mstar = sel[1];
    if (tid < NS) spec[tid] = pspec[pstar*NS + tid];
    __syncthreads();
    float v = -3.0e38f;
    if (tid < NS){
        float acc = c2b[0];
        #pragma unroll
        for (int ch=0; ch<8; ch++){
            float a = c1b[ch];
            #pragma unroll
            for (int k=0;k<5;k++){
                int ss = tid + k - 2;
                if (ss>=0 && ss<NS) a += spec[ss]*c1w[ch*5+k];
            }
            a = fmaxf(a, 0.f);
            acc += a*c2w[ch];
        }
        v = (smask[pstar*NM*NS + mstar*NS + tid]==0) ? NEGV : acc;
    }
    float m = v;
    #pragma unroll
    for (int d=1; d<64; d<<=1) m = fmaxf(m, __shfl_xor(m, d));
    if (lane==0) red[w] = m;
    __syncthreads();
    if (tid==0){
        float mm = red[0];
        #pragma unroll
        for (int i=1;i<8;i++) mm = fmaxf(mm, red[i]);
        maxsh = mm; sel[2] = 1<<30;
    }
    __syncthreads();
    float M2 = maxsh;
    if (tid<NS && v==M2) atomicMin(&sel[2], tid);
    float e = (tid<NS)? expf(v-M2) : 0.f;
    #pragma unroll
    for (int d=1; d<64; d<<=1) e += __shfl_xor(e, d);
    if (lane==0) red[w] = e;
    __syncthreads();
    if (tid==0){
        float se = 0.f;
        #pragma unroll
        for (int i=0;i<8;i++) se += red[i];
        out[0] = (float)pstar;
        out[1] = (float)sel[2];
        out[2] = (float)mstar;
        out[3] = scal[0] + scal[1] - logf(se);
        out[4] = scal[2];
    }
}

extern "C" void kernel_launch(void* const* d_in, const int* in_sizes, int n_in,
                              void* d_out, int out_size, void* d_ws, size_t ws_size,
                              hipStream_t stream) {
    (void)in_sizes; (void)n_in; (void)out_size; (void)ws_size;
    const float* node_feat     = (const float*)d_in[0];
    const float* edge_feat     = (const float*)d_in[1];
    const int*   edge_index    = (const int*)d_in[2];
    const int*   paths         = (const int*)d_in[3];
    const int*   path_mask     = (const int*)d_in[4];
    const float* path_features = (const float*)d_in[5];
    const int*   mod_masks     = (const int*)d_in[6];
    const int*   spec_masks    = (const int*)d_in[7];
    const float* path_spectrum = (const float*)d_in[8];
    const float* W_np  = (const float*)d_in[9];
    const float* b_np  = (const float*)d_in[10];
    const float* W_ep  = (const float*)d_in[11];
    const float* b_ep  = (const float*)d_in[12];
    const float* W_msg = (const float*)d_in[13];
    const float* b_msg = (const float*)d_in[14];
    const float* W_ih  = (const float*)d_in[15];
    const float* b_ih  = (const float*)d_in[16];
    const float* W_hh  = (const float*)d_in[17];
    const float* b_hh  = (const float*)d_in[18];
    const float* W_path = (const float*)d_in[19];
    const float* b_path = (const float*)d_in[20];
    const float* W_mod  = (const float*)d_in[21];
    const float* b_mod  = (const float*)d_in[22];
    const float* c1w = (const float*)d_in[23];
    const float* c1b = (const float*)d_in[24];
    const float* c2w = (const float*)d_in[25];
    const float* c2b = (const float*)d_in[26];
    const float* W_val = (const float*)d_in[27];
    const float* b_val = (const float*)d_in[28];

    char* ws = (char*)d_ws;
    size_t off = 0;
    auto alloc = [&](size_t bytes)->char*{
        char* p = ws + off;
        off += (bytes + 255) & ~(size_t)255;
        return p;
    };
    int*    deg     = (int*)alloc((size_t)NN*4);
    int*    offs    = (int*)alloc((size_t)(NN+1)*4);
    int*    cursor  = (int*)alloc((size_t)NN*4);
    int*    bsum    = (int*)alloc((size_t)NB*4);
    int*    csr_src = (int*)alloc((size_t)NE*4);
    int*    csr_eid = (int*)alloc((size_t)NE*4);
    float*  ef_sum  = (float*)alloc((size_t)NN*FD*4);
    float*  nf_sum  = (float*)alloc((size_t)NN*FD*4);
    float*  Wf      = (float*)alloc((size_t)FD*HD*4);
    float*  bfv     = (float*)alloc((size_t)HD*4);
    ushort* W2T     = (ushort*)alloc((size_t)512*AK*2);
    ushort* A0      = (ushort*)alloc((size_t)NN*AK*2);
    ushort* A1      = (ushort*)alloc((size_t)NN*AK*2);
    ushort* G       = (ushort*)alloc((size_t)NN*512*2);
    float*  gsum    = (float*)alloc((size_t)HD*4);

    hipMemsetAsync(deg, 0, (size_t)NN*4, stream);
    hipMemsetAsync(gsum, 0, (size_t)HD*4, stream);

    k_deg<<<(NE+255)/256, 256, 0, stream>>>(edge_index, deg);
    k_scan1<<<NB, 256, 0, stream>>>(deg, offs, bsum);
    k_scan2<<<1, 256, 0, stream>>>(bsum, offs);
    k_scan3<<<NB, 256, 0, stream>>>(bsum, offs, cursor);
    k_fill<<<(NE+255)/256, 256, 0, stream>>>(edge_index, cursor, csr_src, csr_eid);
    k_gat16<<<NN/4, 256, 0, stream>>>(csr_eid, csr_src, edge_feat, node_feat, offs, ef_sum, nf_sum);
    k_folds<<<9, 256, 0, stream>>>(W_ep, b_ep, W_msg, b_msg, Wf, bfv);
    k_wprep2<<<512, AK, 0, stream>>>(W_ih, W_hh, W_msg, Wf, bfv, b_ih, b_hh, W2T);
    k_prep<<<NN*64/256, 256, 0, stream>>>(node_feat, nf_sum, deg, W_np, b_np, ef_sum, A0, A1);

    const int MB = (NN+127)/128;   // 391
    // iter 1: A0 -> G -> A1.h
    k_gemmG<<<dim3(MB,4), 256, 0, stream>>>(A0, W2T, G);
    k_gruep<<<NN*64/256, 256, 0, stream>>>(G, A0, A1);
    // iter 2: gather(A1) -> G -> A0.h
    k_gather<<<NN/4, 256, 0, stream>>>(A1, offs, csr_src);
    k_gemmG<<<dim3(MB,4), 256, 0, stream>>>(A1, W2T, G);
    k_gruep<<<NN*64/256, 256, 0, stream>>>(G, A1, A0);
    // iter 3: gather(A0) -> G -> A1.h
    k_gather<<<NN/4, 256, 0, stream>>>(A0, offs, csr_src);
    k_gemmG<<<dim3(MB,4), 256, 0, stream>>>(A0, W2T, G);
    k_gruep<<<NN*64/256, 256, 0, stream>>>(G, A0, A1);

    k_sum<<<256, 256, 0, stream>>>(A1, gsum);
    k_small<<<1, 512, 0, stream>>>(edge_feat, paths, path_mask, path_features,
                                   mod_masks, spec_masks, path_spectrum,
                                   W_ep, b_ep, W_path, b_path, W_mod, b_mod,
                                   c1w, c1b, c2w, c2b, W_val, b_val,
                                   gsum, (float*)d_out);
}